// Round 4
// baseline (243.596 us; speedup 1.0000x reference)
//
#include <hip/hip_runtime.h>
#include <math.h>

#define ALPHA  0.1f
#define DT     0.01f
#define EPSV   1e-9f
#define DIFF   10.0f
#define HARD_P 1.5707963267948966f

// Kernel 1 (fused pre): thread i does
//  (a) g[i] = e^{-i*phase[i]} * (x_i + i*y_i);  out[3N:5N] = xy
//  (b) scan src chunk [64i, 64i+64) for segment boundaries -> rowptr
//      (coalesced chunk reads, no dependent-load chains)
__global__ void node_pre(const float2* __restrict__ xy,
                         const float*  __restrict__ phase,
                         const int*    __restrict__ src,
                         float2* __restrict__ g,
                         float2* __restrict__ out_xyold,
                         int*    __restrict__ rowptr,
                         int n, int n_edges) {
    int i = blockIdx.x * blockDim.x + threadIdx.x;

    if (i < n) {
        float2 p = xy[i];
        float ph = phase[i];
        float s, c;
        sincosf(ph, &s, &c);
        float2 gv;
        gv.x = p.x * c + p.y * s;   // e^{-i ph} * (x + iy)
        gv.y = p.y * c - p.x * s;
        g[i] = gv;
        out_xyold[i] = p;
    }

    // boundary scan: chunk i covers edges [64i, 64i+64)
    int n_chunks = (n_edges + 63) >> 6;
    if (i < n_chunks) {
        int base = i << 6;
        int end  = min(base + 64, n_edges);
        int prev = (base == 0) ? -1 : src[base - 1];
        const int4* s4 = (const int4*)(src + base);
        // chunks are 16B-aligned (base multiple of 64)
        for (int q = 0; q < (end - base + 3) / 4; ++q) {
            int4 v = s4[q];
            int vals[4] = {v.x, v.y, v.z, v.w};
            #pragma unroll
            for (int k = 0; k < 4; ++k) {
                int e = base + 4*q + k;
                if (e >= end) break;
                int cur = vals[k];
                if (cur != prev) {
                    for (int r = prev + 1; r <= cur; ++r) rowptr[r] = e;
                    prev = cur;
                }
            }
        }
        if (end == n_edges) {
            // rows past the last src value, plus rowptr[n] = n_edges
            for (int r = prev + 1; r <= n; ++r) rowptr[r] = n_edges;
        }
    }
}

// Kernel 2: one 64-lane wave per node. Coalesced dst reads, independent
// L2 gathers of g[dst], butterfly reduce, lane 0 stores the float2 sum.
// No atomics, no wave-wide epilogue.
__global__ __launch_bounds__(256) void edge_sum(
        const int*    __restrict__ rowptr,
        const int*    __restrict__ dst,
        const float2* __restrict__ g,
        float2* __restrict__ Gsum,
        int n) {
    const int lane = threadIdx.x & 63;
    const int wid  = threadIdx.x >> 6;
    const int node = blockIdx.x * (blockDim.x >> 6) + wid;
    if (node >= n) return;

    const int e0 = rowptr[node];
    const int e1 = rowptr[node + 1];

    float ax = 0.f, ay = 0.f;
    for (int e = e0 + lane; e < e1; e += 64) {
        int d = dst[e];          // coalesced across lanes
        float2 gd = g[d];        // L2-resident gather
        ax += gd.x; ay += gd.y;
    }
    #pragma unroll
    for (int off = 32; off > 0; off >>= 1) {
        ax += __shfl_xor(ax, off);
        ay += __shfl_xor(ay, off);
    }
    if (lane == 0) {
        float2 v; v.x = ax; v.y = ay;
        Gsum[node] = v;
    }
}

// Kernel 3: dense per-node epilogue (1 thread/node).
__global__ void node_post(const float2* __restrict__ xy,
                          const float2* __restrict__ xyd,
                          const float*  __restrict__ phase,
                          const float*  __restrict__ w,
                          const float*  __restrict__ amps,
                          const float*  __restrict__ ha,
                          const float2* __restrict__ Gsum,
                          float* __restrict__ out,
                          int n) {
    int i = blockIdx.x * blockDim.x + threadIdx.x;
    if (i >= n) return;
    float2 p   = xy[i];
    float2 pdv = xyd[i];
    float x = p.x, y = p.y;
    float xd = pdv.x, yd = pdv.y;

    float r2 = x*x + y*y;
    float a = ALPHA * (1.0f - r2*r2);
    float h = ha[i];
    float zeta = 1.0f - h * ((xd + EPSV) / (fabsf(xd) + EPSV));
    float b = w[i] / (zeta + EPSV);
    float kx = a*x - b*y;
    float ky = b*x + a*y;

    float2 gv = Gsum[i];
    float s, c;
    sincosf(phase[i], &s, &c);
    float sumx = c*gv.x - s*gv.y;   // rotate by e^{+i*phase}
    float sumy = s*gv.x + c*gv.y;

    float xdot = fminf(fmaxf(kx + sumx, xd - DIFF), xd + DIFF);
    float ydot = fminf(fmaxf(ky + sumy, yd - DIFF), yd + DIFF);
    float xn = x + xdot * DT;
    float yn = y + ydot * DT;

    float ang = fminf(fmaxf(amps[i] * yn, -HARD_P), HARD_P);

    out[i] = ang;
    float2* xy_new = (float2*)(out + n);
    float2 v; v.x = xn; v.y = yn;
    xy_new[i] = v;
}

extern "C" void kernel_launch(void* const* d_in, const int* in_sizes, int n_in,
                              void* d_out, int out_size, void* d_ws, size_t ws_size,
                              hipStream_t stream) {
    const float2* xy    = (const float2*)d_in[0];
    const float2* xyd   = (const float2*)d_in[1];
    const float*  phase = (const float*)d_in[2];
    const float*  w     = (const float*)d_in[3];
    const float*  amps  = (const float*)d_in[4];
    const float*  ha    = (const float*)d_in[5];
    const int*    esrc  = (const int*)d_in[6];
    const int*    edst  = (const int*)d_in[7];

    const int n       = in_sizes[2];
    const int n_edges = in_sizes[6];

    float* out = (float*)d_out;

    // ws: g float2[n] | Gsum float2[n] | rowptr int[n+1]
    float2* g      = (float2*)d_ws;
    float2* Gsum   = (float2*)((char*)d_ws + (size_t)n * sizeof(float2));
    int*    rowptr = (int*)((char*)d_ws + (size_t)2 * n * sizeof(float2));

    const int B = 256;
    int n_chunks = (n_edges + 63) >> 6;
    int pre_items = (n > n_chunks) ? n : n_chunks;
    node_pre<<<(pre_items + B - 1) / B, B, 0, stream>>>(
        xy, phase, esrc, g, (float2*)(out + (size_t)3 * n), rowptr, n, n_edges);

    const int nodes_per_block = B / 64;
    edge_sum<<<(n + nodes_per_block - 1) / nodes_per_block, B, 0, stream>>>(
        rowptr, edst, g, Gsum, n);

    node_post<<<(n + B - 1) / B, B, 0, stream>>>(
        xy, xyd, phase, w, amps, ha, Gsum, out, n);
}

// Round 5
// 204.085 us; speedup vs baseline: 1.1936x; 1.1936x over previous
//
#include <hip/hip_runtime.h>
#include <math.h>

#define ALPHA  0.1f
#define DT     0.01f
#define EPSV   1e-9f
#define DIFF   10.0f
#define HARD_P 1.5707963267948966f

// Kernel 1: per-node precompute (cheap, dense).
//   g[i] = e^{-i*phase[i]} * (x_i + i*y_i)
//   out[3N:5N] = xy  (xy_dot_old_new)
//   Gsum[i] = 0      (atomic target; ws is re-poisoned before every call)
__global__ void node_pre(const float2* __restrict__ xy,
                         const float*  __restrict__ phase,
                         float2* __restrict__ g,
                         float2* __restrict__ out_xyold,
                         float2* __restrict__ Gsum,
                         int n) {
    int i = blockIdx.x * blockDim.x + threadIdx.x;
    if (i >= n) return;
    float2 p = xy[i];
    float ph = phase[i];
    float s, c;
    sincosf(ph, &s, &c);
    float2 gv;
    gv.x = p.x * c + p.y * s;   // e^{-i ph} * (x + iy)
    gv.y = p.y * c - p.x * s;
    g[i] = gv;
    out_xyold[i] = p;
    float2 z; z.x = 0.f; z.y = 0.f;
    Gsum[i] = z;
}

// Kernel 2: edge-parallel segmented reduction. One lane per edge.
// Coalesced nontemporal src/dst streams, L2-resident g gather,
// in-wave segmented inclusive scan keyed by (sorted) src,
// segment-tail lanes atomicAdd float2 partials. No rowptr.
__global__ __launch_bounds__(256) void edge_seg(
        const int*    __restrict__ src,
        const int*    __restrict__ dst,
        const float2* __restrict__ g,
        float* __restrict__ Gsum,
        int n_edges) {
    const int e    = blockIdx.x * blockDim.x + threadIdx.x;
    const int lane = threadIdx.x & 63;
    const bool valid = (e < n_edges);

    int s = valid ? __builtin_nontemporal_load(src + e) : -1;
    int d = valid ? __builtin_nontemporal_load(dst + e) : 0;

    float ax = 0.f, ay = 0.f;
    if (valid) {
        float2 gd = g[d];     // random 8B gather, L2/L3-resident
        ax = gd.x; ay = gd.y;
    }

    // Segmented inclusive scan: add from lane-off iff same src key.
    // Keys are sorted, so key equality at distance off implies the whole
    // intervening run shares the key.
    #pragma unroll
    for (int off = 1; off < 64; off <<= 1) {
        float px = __shfl_up(ax, off);
        float py = __shfl_up(ay, off);
        int   ps = __shfl_up(s,  off);
        if (lane >= off && ps == s) { ax += px; ay += py; }
    }

    // Tail lane of each segment flushes the partial sum.
    int snext = __shfl_down(s, 1);
    bool tail = (lane == 63) || (snext != s);
    if (valid && tail) {
        atomicAdd(&Gsum[2*s],     ax);
        atomicAdd(&Gsum[2*s + 1], ay);
    }
}

// Kernel 3: dense per-node epilogue (1 thread/node).
__global__ void node_post(const float2* __restrict__ xy,
                          const float2* __restrict__ xyd,
                          const float*  __restrict__ phase,
                          const float*  __restrict__ w,
                          const float*  __restrict__ amps,
                          const float*  __restrict__ ha,
                          const float2* __restrict__ Gsum,
                          float* __restrict__ out,
                          int n) {
    int i = blockIdx.x * blockDim.x + threadIdx.x;
    if (i >= n) return;
    float2 p   = xy[i];
    float2 pdv = xyd[i];
    float x = p.x, y = p.y;
    float xd = pdv.x, yd = pdv.y;

    float r2 = x*x + y*y;
    float a = ALPHA * (1.0f - r2*r2);
    float h = ha[i];
    float zeta = 1.0f - h * ((xd + EPSV) / (fabsf(xd) + EPSV));
    float b = w[i] / (zeta + EPSV);
    float kx = a*x - b*y;
    float ky = b*x + a*y;

    float2 gv = Gsum[i];
    float s, c;
    sincosf(phase[i], &s, &c);
    float sumx = c*gv.x - s*gv.y;   // rotate by e^{+i*phase}
    float sumy = s*gv.x + c*gv.y;

    float xdot = fminf(fmaxf(kx + sumx, xd - DIFF), xd + DIFF);
    float ydot = fminf(fmaxf(ky + sumy, yd - DIFF), yd + DIFF);
    float xn = x + xdot * DT;
    float yn = y + ydot * DT;

    float ang = fminf(fmaxf(amps[i] * yn, -HARD_P), HARD_P);

    out[i] = ang;
    float2* xy_new = (float2*)(out + n);
    float2 v; v.x = xn; v.y = yn;
    xy_new[i] = v;
}

extern "C" void kernel_launch(void* const* d_in, const int* in_sizes, int n_in,
                              void* d_out, int out_size, void* d_ws, size_t ws_size,
                              hipStream_t stream) {
    const float2* xy    = (const float2*)d_in[0];
    const float2* xyd   = (const float2*)d_in[1];
    const float*  phase = (const float*)d_in[2];
    const float*  w     = (const float*)d_in[3];
    const float*  amps  = (const float*)d_in[4];
    const float*  ha    = (const float*)d_in[5];
    const int*    esrc  = (const int*)d_in[6];
    const int*    edst  = (const int*)d_in[7];

    const int n       = in_sizes[2];
    const int n_edges = in_sizes[6];

    float* out = (float*)d_out;

    // ws: g float2[n] | Gsum float2[n]
    float2* g    = (float2*)d_ws;
    float2* Gsum = (float2*)((char*)d_ws + (size_t)n * sizeof(float2));

    const int B = 256;
    node_pre<<<(n + B - 1) / B, B, 0, stream>>>(
        xy, phase, g, (float2*)(out + (size_t)3 * n), Gsum, n);

    edge_seg<<<(n_edges + B - 1) / B, B, 0, stream>>>(
        esrc, edst, g, (float*)Gsum, n_edges);

    node_post<<<(n + B - 1) / B, B, 0, stream>>>(
        xy, xyd, phase, w, amps, ha, Gsum, out, n);
}

// Round 7
// 199.945 us; speedup vs baseline: 1.2183x; 1.0207x over previous
//
#include <hip/hip_runtime.h>
#include <math.h>
#include <limits.h>

#define ALPHA  0.1f
#define DT     0.01f
#define EPSV   1e-9f
#define DIFF   10.0f
#define HARD_P 1.5707963267948966f

typedef int v4i __attribute__((ext_vector_type(4)));   // clang vector: OK for nontemporal builtins

// Kernel 1: per-node precompute (dense, cheap).
//   g[i] = e^{-i*phase[i]} * (x_i + i*y_i)
//   out[3N:5N] = xy  (xy_dot_old_new)
//   Gsum[i] = 0      (atomic target)
__global__ void node_pre(const float2* __restrict__ xy,
                         const float*  __restrict__ phase,
                         float2* __restrict__ g,
                         float2* __restrict__ out_xyold,
                         float2* __restrict__ Gsum,
                         int n) {
    int i = blockIdx.x * blockDim.x + threadIdx.x;
    if (i >= n) return;
    float2 p = xy[i];
    float ph = phase[i];
    float s, c;
    sincosf(ph, &s, &c);
    float2 gv;
    gv.x = p.x * c + p.y * s;   // e^{-i ph} * (x + iy)
    gv.y = p.y * c - p.x * s;
    g[i] = gv;
    out_xyold[i] = p;
    float2 z; z.x = 0.f; z.y = 0.f;
    Gsum[i] = z;
}

// Kernel 2: edge-parallel segmented reduction, 4 edges per lane.
// Lane loads int4 src/dst (coalesced), gathers 4 independent g[dst],
// locally combines runs (sorted keys; interior runs -> rare atomics),
// then ONE wave segmented scan over per-lane (last-key, suffix-sum)
// aggregates. Tail lanes / first-run-closers flush via atomicAdd.
__global__ __launch_bounds__(256) void edge_seg4(
        const int*    __restrict__ src,
        const int*    __restrict__ dst,
        const float2* __restrict__ g,
        float* __restrict__ Gsum,
        int n_edges) {
    const int lane = threadIdx.x & 63;
    const int wib  = threadIdx.x >> 6;
    const long wave = (long)blockIdx.x * 4 + wib;        // 4 waves / block
    const long base = wave * 256 + (long)lane * 4;       // this lane's 4 edges

    int   sk[4];
    float vx[4], vy[4];

    if (base + 3 < (long)n_edges) {
        v4i sv = __builtin_nontemporal_load((const v4i*)(src + base));
        v4i dv = __builtin_nontemporal_load((const v4i*)(dst + base));
        sk[0]=sv.x; sk[1]=sv.y; sk[2]=sv.z; sk[3]=sv.w;
        // 4 independent L2-resident gathers in flight
        float2 g0 = g[dv.x];
        float2 g1 = g[dv.y];
        float2 g2 = g[dv.z];
        float2 g3 = g[dv.w];
        vx[0]=g0.x; vy[0]=g0.y; vx[1]=g1.x; vy[1]=g1.y;
        vx[2]=g2.x; vy[2]=g2.y; vx[3]=g3.x; vy[3]=g3.y;
    } else {
        #pragma unroll
        for (int j = 0; j < 4; ++j) {
            long e = base + j;
            if (e < (long)n_edges) {
                sk[j] = src[e];
                float2 gd = g[dst[e]];
                vx[j] = gd.x; vy[j] = gd.y;
            } else {
                sk[j] = INT_MAX;    // > all real keys, preserves sortedness
                vx[j] = 0.f; vy[j] = 0.f;
            }
        }
    }

    // ---- local run combine ----
    int   kF = sk[0], rk = sk[0];
    float fx = 0.f, fy = 0.f;            // first-run sum (once closed)
    float rx = vx[0], ry = vy[0];        // current-run sum
    bool  firstClosed = false;
    #pragma unroll
    for (int j = 1; j < 4; ++j) {
        if (sk[j] == rk) {
            rx += vx[j]; ry += vy[j];
        } else {
            if (!firstClosed) { fx = rx; fy = ry; firstClosed = true; }
            else {
                // interior complete run (rare: needs 2+ boundaries in 4 edges)
                atomicAdd(&Gsum[2*rk],   rx);
                atomicAdd(&Gsum[2*rk+1], ry);
            }
            rk = sk[j]; rx = vx[j]; ry = vy[j];
        }
    }
    const int  kL   = rk;
    const bool pure = !firstClosed;      // whole lane one key

    // ---- wave segmented inclusive scan over (kL, suffix-sum) ----
    // Correct because keys are sorted: equal kL at distance implies all
    // intervening lanes are pure with the same key.
    float ax = rx, ay = ry;
    int   key = kL;
    #pragma unroll
    for (int off = 1; off < 64; off <<= 1) {
        float px = __shfl_up(ax, off);
        float py = __shfl_up(ay, off);
        int   pk = __shfl_up(key, off);
        if (lane >= off && pk == key) { ax += px; ay += py; }
    }

    // ---- flushes ----
    float pscx = __shfl_up(ax, 1);
    float pscy = __shfl_up(ay, 1);
    int   pKL  = __shfl_up(key, 1);
    int   nKF  = __shfl_down(kF, 1);

    // (1) non-pure lane closes its first run (absorbing carry from prev lanes)
    if (!pure) {                          // kF < kL <= INT_MAX, so kF valid
        float gx_ = fx, gy_ = fy;
        if (lane > 0 && pKL == kF) { gx_ += pscx; gy_ += pscy; }
        atomicAdd(&Gsum[2*kF],   gx_);
        atomicAdd(&Gsum[2*kF+1], gy_);
    }
    // (2) last run ends at a lane boundary (or wave end): flush scan result
    bool endHere = (lane == 63) || (nKF != key);
    if (key != INT_MAX && endHere) {
        atomicAdd(&Gsum[2*key],   ax);
        atomicAdd(&Gsum[2*key+1], ay);
    }
}

// Kernel 3: dense per-node epilogue (1 thread/node).
__global__ void node_post(const float2* __restrict__ xy,
                          const float2* __restrict__ xyd,
                          const float*  __restrict__ phase,
                          const float*  __restrict__ w,
                          const float*  __restrict__ amps,
                          const float*  __restrict__ ha,
                          const float2* __restrict__ Gsum,
                          float* __restrict__ out,
                          int n) {
    int i = blockIdx.x * blockDim.x + threadIdx.x;
    if (i >= n) return;
    float2 p   = xy[i];
    float2 pdv = xyd[i];
    float x = p.x, y = p.y;
    float xd = pdv.x, yd = pdv.y;

    float r2 = x*x + y*y;
    float a = ALPHA * (1.0f - r2*r2);
    float h = ha[i];
    float zeta = 1.0f - h * ((xd + EPSV) / (fabsf(xd) + EPSV));
    float b = w[i] / (zeta + EPSV);
    float kx = a*x - b*y;
    float ky = b*x + a*y;

    float2 gv = Gsum[i];
    float s, c;
    sincosf(phase[i], &s, &c);
    float sumx = c*gv.x - s*gv.y;   // rotate by e^{+i*phase}
    float sumy = s*gv.x + c*gv.y;

    float xdot = fminf(fmaxf(kx + sumx, xd - DIFF), xd + DIFF);
    float ydot = fminf(fmaxf(ky + sumy, yd - DIFF), yd + DIFF);
    float xn = x + xdot * DT;
    float yn = y + ydot * DT;

    float ang = fminf(fmaxf(amps[i] * yn, -HARD_P), HARD_P);

    out[i] = ang;
    float2* xy_new = (float2*)(out + n);
    float2 v; v.x = xn; v.y = yn;
    xy_new[i] = v;
}

extern "C" void kernel_launch(void* const* d_in, const int* in_sizes, int n_in,
                              void* d_out, int out_size, void* d_ws, size_t ws_size,
                              hipStream_t stream) {
    const float2* xy    = (const float2*)d_in[0];
    const float2* xyd   = (const float2*)d_in[1];
    const float*  phase = (const float*)d_in[2];
    const float*  w     = (const float*)d_in[3];
    const float*  amps  = (const float*)d_in[4];
    const float*  ha    = (const float*)d_in[5];
    const int*    esrc  = (const int*)d_in[6];
    const int*    edst  = (const int*)d_in[7];

    const int n       = in_sizes[2];
    const int n_edges = in_sizes[6];

    float* out = (float*)d_out;

    // ws: g float2[n] | Gsum float2[n]
    float2* g    = (float2*)d_ws;
    float2* Gsum = (float2*)((char*)d_ws + (size_t)n * sizeof(float2));

    const int B = 256;
    node_pre<<<(n + B - 1) / B, B, 0, stream>>>(
        xy, phase, g, (float2*)(out + (size_t)3 * n), Gsum, n);

    // each block: 4 waves x 256 edges = 1024 edges
    int n_blocks = (n_edges + 1023) / 1024;
    edge_seg4<<<n_blocks, B, 0, stream>>>(esrc, edst, g, (float*)Gsum, n_edges);

    node_post<<<(n + B - 1) / B, B, 0, stream>>>(
        xy, xyd, phase, w, amps, ha, Gsum, out, n);
}